// Round 7
// baseline (2526.943 us; speedup 1.0000x reference)
//
#include <hip/hip_runtime.h>
#include <hip/hip_bf16.h>

#define N_ATOMS 25000
#define N_PAIRS 500000
#define DEPTH 4

typedef _Float16 f16x8 __attribute__((ext_vector_type(8)));
typedef float f32x16 __attribute__((ext_vector_type(16)));
typedef unsigned short u16;

__device__ __forceinline__ float tanh_fast(float x) {
    float e = __expf(2.0f * x);
    return 1.0f - 2.0f * __builtin_amdgcn_rcpf(e + 1.0f);
}

__device__ __forceinline__ void split_h(float x, u16& hi, u16& lo) {
    _Float16 h = (_Float16)x;
    _Float16 l = (_Float16)(x - (float)h);
    hi = *(u16*)&h;
    lo = *(u16*)&l;
}

// ---------------- prep: split weights to hi/lo fp16, fragment-major images
// img1 per depth: [hl][ntw][ks(8)][l(64)][j(8)]        = 16384 u16
// img2 per depth: [hl][ntw][t(4)][ks(4)][l][j]         = 32768 u16  (cols permuted: n=4*ch+t)
// imgab per depth: [stage][hl][ntw][ks(4)][l][j]       = 16384 u16
__global__ __launch_bounds__(256)
void prep_kernel(const float* __restrict__ piW1, const float* __restrict__ piW2,
                 const float* __restrict__ iiW1, const float* __restrict__ iiW2,
                 u16* __restrict__ img1, u16* __restrict__ img2, u16* __restrict__ imgab) {
    int gid = blockIdx.x * 256 + threadIdx.x;
    int d = gid >> 15, e = gid & 32767;
    u16 hi, lo;
    if (e < 8192) {                 // W1 [k=128][n=64]
        int k = e >> 6, n = e & 63;
        split_h(piW1[d * 8192 + e], hi, lo);
        int ntw = n >> 5, colb = n & 31;
        int ks = k >> 4, lh = (k >> 3) & 1, j = k & 7;
        int off = ((ntw * 8 + ks) * 64 + lh * 32 + colb) * 8 + j;
        img1[d * 16384 + 0 * 8192 + off] = hi;
        img1[d * 16384 + 1 * 8192 + off] = lo;
    } else if (e < 24576) {         // W2 [k=64][n=256], permuted n = 4*ch + t
        int s = e - 8192;
        int k = s >> 8, n = s & 255;
        split_h(piW2[d * 16384 + s], hi, lo);
        int ch = n >> 2, t = n & 3;
        int ntw = ch >> 5, colb = ch & 31;
        int ks = k >> 4, lh = (k >> 3) & 1, j = k & 7;
        int off = (((ntw * 4 + t) * 4 + ks) * 64 + lh * 32 + colb) * 8 + j;
        img2[d * 32768 + 0 * 16384 + off] = hi;
        img2[d * 32768 + 1 * 16384 + off] = lo;
    } else {                        // Wa (stage0) / Wb (stage1), [k=64][n=64]
        int stage = (e < 28672) ? 0 : 1;
        int s = e - (stage ? 28672 : 24576);
        int k = s >> 6, n = s & 63;
        float x = stage ? iiW2[d * 4096 + s] : iiW1[d * 4096 + s];
        split_h(x, hi, lo);
        int ntw = n >> 5, colb = n & 31;
        int ks = k >> 4, lh = (k >> 3) & 1, j = k & 7;
        int off = ((ntw * 4 + ks) * 64 + lh * 32 + colb) * 8 + j;
        imgab[d * 16384 + (stage * 2 + 0) * 4096 + off] = hi;
        imgab[d * 16384 + (stage * 2 + 1) * 4096 + off] = lo;
    }
}

__global__ __launch_bounds__(256)
void prep_b2(const float* __restrict__ piB2, float* __restrict__ b2p) {
    int d = blockIdx.x, n = threadIdx.x;
    int ch = n >> 2, t = n & 3;
    int np = (ch >> 5) * 128 + t * 32 + (ch & 31);
    b2p[d * 256 + np] = piB2[d * 256 + n];
}

// ---------------- atom-level MLP (fp32 VALU), h stored split fp16
template <int K, bool IS_D0>
__global__ __launch_bounds__(256)
void atom_mlp(const float* __restrict__ p_in,
              const float* __restrict__ W1, const float* __restrict__ b1,
              const float* __restrict__ W2, const float* __restrict__ b2,
              const float* __restrict__ res0_w,
              _Float16* __restrict__ h_hi, _Float16* __restrict__ h_lo,
              float* __restrict__ acc_out) {
    __shared__ float sP[4][64];
    __shared__ float sH[4][64];
    int tid = threadIdx.x;
    int al = tid >> 6, c = tid & 63;
    int a = blockIdx.x * 4 + al;
    if (c < K) sP[al][c] = p_in[a * K + c];
    __syncthreads();
    float s = b1[c];
#pragma unroll
    for (int k = 0; k < K; ++k) s += sP[al][k] * W1[k * 64 + c];
    float t1 = tanh_fast(s);
    float r;
    if (IS_D0) {
        r = 0.f;
#pragma unroll
        for (int k = 0; k < 16; ++k) r += sP[al][k] * res0_w[k * 64 + c];
    } else {
        r = sP[al][c];
    }
    acc_out[a * 64 + c] = r;
    sH[al][c] = t1;
    __syncthreads();
    float s2 = b2[c];
#pragma unroll
    for (int k = 0; k < 64; ++k) s2 += sH[al][k] * W2[k * 64 + c];
    float hv = tanh_fast(s2);
    _Float16 hb = (_Float16)hv;
    h_hi[a * 64 + c] = hb;
    h_lo[a * 64 + c] = (_Float16)(hv - (float)hb);
}

// ---------------- output head (fp32)
__global__ __launch_bounds__(256)
void out_kernel(const float* __restrict__ p,
                const float* __restrict__ W1, const float* __restrict__ b1,
                const float* __restrict__ W2, const float* __restrict__ b2,
                const float* __restrict__ wo,
                float* __restrict__ out, int store) {
    __shared__ float sP[4][64];
    __shared__ float sH[4][64];
    int tid = threadIdx.x;
    int al = tid >> 6, c = tid & 63;
    int a = blockIdx.x * 4 + al;
    sP[al][c] = p[a * 64 + c];
    __syncthreads();
    float s = b1[c];
#pragma unroll
    for (int k = 0; k < 64; ++k) s += sP[al][k] * W1[k * 64 + c];
    sH[al][c] = tanh_fast(s);
    __syncthreads();
    float s2 = b2[c];
#pragma unroll
    for (int k = 0; k < 64; ++k) s2 += sH[al][k] * W2[k * 64 + c];
    float v = tanh_fast(s2) * wo[c];
#pragma unroll
    for (int off = 32; off > 0; off >>= 1) v += __shfl_down(v, off, 64);
    if (c == 0) {
        if (store) out[a] = v;
        else out[a] += v;
    }
}

// ---------------- fused pair pipeline: fp16 MFMA, staged coalesced gather,
// swizzled fragment LDS (0 conflicts), weights streamed from global (L2-hot),
// 66.5 KB LDS -> 2 blocks/CU
#define MFMA __builtin_amdgcn_mfma_f32_32x32x16_f16

__global__ __launch_bounds__(512, 4)
void pair_kernel(const _Float16* __restrict__ hhi,
                 const _Float16* __restrict__ hlo,
                 const int* __restrict__ ind2,
                 const float* __restrict__ basis,
                 const u16* __restrict__ img1,
                 const u16* __restrict__ img2,
                 const u16* __restrict__ imgab,
                 const float* __restrict__ piB1,
                 const float* __restrict__ b2p,
                 float* __restrict__ accp) {
    __shared__ __attribute__((aligned(16))) _Float16 sA[16384];    // 32 KB pij-hi frags; [0:8192] re-used as inter frags
    __shared__ __attribute__((aligned(16))) _Float16 sAlo[8192];   // 16 KB pij-lo (i-half) frags
    __shared__ __attribute__((aligned(16))) _Float16 sPing[8192];  // 16 KB
    __shared__ float sBas[128 * 4];                                //  2 KB
    __shared__ int sIdx[128];                                      // 0.5 KB
    // total 66.5 KB -> 2 blocks/CU, 16 waves/CU
    _Float16* sInter = sA;   // alias: pij dead after G1; gather in G4 re-fills after G3

    const int tid = threadIdx.x;
    const int l = tid & 63;
    const int w = tid >> 6;
    const int mt = w >> 1, ntw = w & 1;
    const int col = l & 31, kg = l >> 5;
    const int ch = ntw * 32 + col;
    const int chks = ch >> 4, chlh = (ch >> 3) & 1, chj = ch & 7;
    // swizzled C-store / A-read addressing (verified R6: conflicts == 0)
    const int rr2 = (chks * 2 + chlh) ^ (kg << 2);
    const int cbase = (mt * 4 + chks) * 512 + chlh * 256 + (rr2 << 3) + chj;
    const int abase = kg * 256 + ((col ^ kg) << 3);

    const float b1v = piB1[ch];
    float b2v[4];
#pragma unroll
    for (int t = 0; t < 4; ++t) b2v[t] = b2p[ntw * 128 + t * 32 + col];

    const int nTiles = (N_PAIRS + 127) >> 7;

    // cooperative staged gather: coalesced 16B chunks, each h row read once per tile
    auto gather = [&](int tile) {
        int base = tile << 7;
#pragma unroll
        for (int it = 0; it < 6; ++it) {
            int id = it * 512 + tid;
            if (id < 2048) {            // hi: both halves, K=128
                int m = id >> 4, half = (id >> 3) & 1, seg = id & 7;
                int p = min(base + m, N_PAIRS - 1);
                int row = ind2[2 * p + half];
                uint4 v = *(const uint4*)(hhi + row * 64 + seg * 8);
                int mtd = m >> 5, lrow = m & 31;
                int ks = half * 4 + (seg >> 1), lh = seg & 1;
                *(uint4*)(sA + ((mtd * 8 + ks) * 64 + lh * 32 + lrow) * 8) = v;
            } else {                    // lo: i-half only, K=64
                int e = id - 2048;
                int m = e >> 3, seg = e & 7;
                int p = min(base + m, N_PAIRS - 1);
                int row = ind2[2 * p];
                uint4 v = *(const uint4*)(hlo + row * 64 + seg * 8);
                int mtd = m >> 5, lrow = m & 31;
                int ks = seg >> 1, lh = seg & 1;
                *(uint4*)(sAlo + ((mtd * 4 + ks) * 64 + lh * 32 + lrow) * 8) = v;
            }
        }
    };
    gather(blockIdx.x);
    __syncthreads();

    for (int tile = blockIdx.x; tile < nTiles; tile += gridDim.x) {
        const int base = tile << 7;

        // ---- G1: stage basis/idx; [128x128]@[128x64]+b1 (+h_i lo corr), tanh -> sPing
        if (tid < 128) {
            int pc = min(base + tid, N_PAIRS - 1);
            *(float4*)&sBas[tid * 4] = ((const float4*)basis)[pc];
            sIdx[tid] = ind2[2 * pc];
        }
        {
            f32x16 acc = {};
            const _Float16* ap = sA + mt * 4096 + l * 8;
            const _Float16* alop = sAlo + mt * 2048 + l * 8;
            const u16* w1h = img1 + ntw * 4096 + l * 8;
            const u16* w1l = img1 + 8192 + ntw * 4096 + l * 8;
#pragma unroll
            for (int ks = 0; ks < 8; ++ks) {
                f16x8 a = *(const f16x8*)(ap + ks * 512);
                acc = MFMA(a, *(const f16x8*)(w1h + ks * 512), acc, 0, 0, 0);
                acc = MFMA(a, *(const f16x8*)(w1l + ks * 512), acc, 0, 0, 0);
            }
#pragma unroll
            for (int ks = 0; ks < 4; ++ks) {   // h_i lo correction (i-half = k 0..63)
                f16x8 a = *(const f16x8*)(alop + ks * 512);
                acc = MFMA(a, *(const f16x8*)(w1h + ks * 512), acc, 0, 0, 0);
            }
#pragma unroll
            for (int r = 0; r < 16; ++r) {
                const int Lc = (r & 3) + 8 * (r >> 2);
                sPing[cbase ^ (Lc << 3)] = (_Float16)tanh_fast(acc[r] + b1v);
            }
        }
        __syncthreads();

        // ---- G2: [128x64]@[64x256]+b2 (W2 hi+lo from global), tanh, basis contraction -> sInter
        {
            float inter[16];
#pragma unroll
            for (int r = 0; r < 16; ++r) inter[r] = 0.f;
#pragma unroll
            for (int tp = 0; tp < 2; ++tp) {
                f32x16 acc0 = {}, acc1 = {};
                const int t0 = tp * 2, t1 = tp * 2 + 1;
#pragma unroll
                for (int ks = 0; ks < 4; ++ks) {
                    f16x8 a = *(const f16x8*)(sPing + ((mt * 4 + ks) * 512 + (abase ^ (ks << 4))));
                    const u16* bh0 = img2 + ((ntw * 4 + t0) * 4 + ks) * 512 + l * 8;
                    const u16* bh1 = img2 + ((ntw * 4 + t1) * 4 + ks) * 512 + l * 8;
                    const u16* bl0 = img2 + 16384 + ((ntw * 4 + t0) * 4 + ks) * 512 + l * 8;
                    const u16* bl1 = img2 + 16384 + ((ntw * 4 + t1) * 4 + ks) * 512 + l * 8;
                    acc0 = MFMA(a, *(const f16x8*)bh0, acc0, 0, 0, 0);
                    acc0 = MFMA(a, *(const f16x8*)bl0, acc0, 0, 0, 0);
                    acc1 = MFMA(a, *(const f16x8*)bh1, acc1, 0, 0, 0);
                    acc1 = MFMA(a, *(const f16x8*)bl1, acc1, 0, 0, 0);
                }
#pragma unroll
                for (int r = 0; r < 16; ++r) {
                    const int Lc = (r & 3) + 8 * (r >> 2);
                    const int row = mt * 32 + Lc + 4 * kg;
                    float4 bas = *(const float4*)&sBas[row * 4];
                    float bA = tp ? bas.z : bas.x;
                    float bB = tp ? bas.w : bas.y;
                    inter[r] += tanh_fast(acc0[r] + b2v[t0]) * bA
                              + tanh_fast(acc1[r] + b2v[t1]) * bB;
                }
            }
#pragma unroll
            for (int r = 0; r < 16; ++r) {
                const int Lc = (r & 3) + 8 * (r >> 2);
                sInter[cbase ^ (Lc << 3)] = (_Float16)inter[r];
            }
        }
        __syncthreads();

        // ---- G3: inter @ ii_w1 (hi), tanh -> sPing
        {
            f32x16 acc = {};
#pragma unroll
            for (int ks = 0; ks < 4; ++ks) {
                f16x8 a = *(const f16x8*)(sInter + ((mt * 4 + ks) * 512 + (abase ^ (ks << 4))));
                f16x8 fwa = *(const f16x8*)(imgab + ntw * 2048 + ks * 512 + l * 8);
                acc = MFMA(a, fwa, acc, 0, 0, 0);
            }
#pragma unroll
            for (int r = 0; r < 16; ++r) {
                const int Lc = (r & 3) + 8 * (r >> 2);
                sPing[cbase ^ (Lc << 3)] = (_Float16)tanh_fast(acc[r]);
            }
        }
        __syncthreads();

        // ---- G4: @ ii_w2 (hi), tanh, atomic scatter; overlap next-tile gather
        {
            gather(tile + gridDim.x);   // writes sA/sAlo only; G4 reads sPing (disjoint)

            f32x16 acc = {};
#pragma unroll
            for (int ks = 0; ks < 4; ++ks) {
                f16x8 a = *(const f16x8*)(sPing + ((mt * 4 + ks) * 512 + (abase ^ (ks << 4))));
                f16x8 fwb = *(const f16x8*)(imgab + 8192 + ntw * 2048 + ks * 512 + l * 8);
                acc = MFMA(a, fwb, acc, 0, 0, 0);
            }
#pragma unroll
            for (int r = 0; r < 16; ++r) {
                const int Lc = (r & 3) + 8 * (r >> 2);
                const int lrow = Lc + 4 * kg;
                const int p = base + mt * 32 + lrow;
                if (p < N_PAIRS)
                    atomicAdd(&accp[sIdx[mt * 32 + lrow] * 64 + ch], tanh_fast(acc[r]));
            }
        }
        __syncthreads();
    }
}

extern "C" void kernel_launch(void* const* d_in, const int* in_sizes, int n_in,
                              void* d_out, int out_size, void* d_ws, size_t ws_size,
                              hipStream_t stream) {
    const int* ind2 = (const int*)d_in[0];
    const float* prop = (const float*)d_in[1];
    const float* basis = (const float*)d_in[2];
    const float* pp0_w1 = (const float*)d_in[3];
    const float* pp0_b1 = (const float*)d_in[4];
    const float* pp_w1 = (const float*)d_in[5];
    const float* pp_b1 = (const float*)d_in[6];
    const float* pp_w2 = (const float*)d_in[7];
    const float* pp_b2 = (const float*)d_in[8];
    const float* pi_w1 = (const float*)d_in[9];
    const float* pi_b1 = (const float*)d_in[10];
    const float* pi_w2 = (const float*)d_in[11];
    const float* pi_b2 = (const float*)d_in[12];
    const float* ii_w1 = (const float*)d_in[13];
    const float* ii_w2 = (const float*)d_in[14];
    const float* res0_w = (const float*)d_in[15];
    const float* out_w1 = (const float*)d_in[16];
    const float* out_b1 = (const float*)d_in[17];
    const float* out_w2 = (const float*)d_in[18];
    const float* out_b2 = (const float*)d_in[19];
    const float* out_wo = (const float*)d_in[20];
    float* out = (float*)d_out;

    float* B0 = (float*)d_ws;
    float* B1 = B0 + N_ATOMS * 64;
    _Float16* Hhi = (_Float16*)(B1 + N_ATOMS * 64);
    _Float16* Hlo = Hhi + N_ATOMS * 64;
    u16* img1 = (u16*)(Hlo + N_ATOMS * 64);
    u16* img2 = img1 + 4 * 16384;
    u16* imgab = img2 + 4 * 32768;
    float* b2p = (float*)(imgab + 4 * 16384);
    float* pbuf[2] = {B0, B1};

    prep_kernel<<<512, 256, 0, stream>>>(pi_w1, pi_w2, ii_w1, ii_w2, img1, img2, imgab);
    prep_b2<<<4, 256, 0, stream>>>(pi_b2, b2p);

    for (int d = 0; d < DEPTH; ++d) {
        float* acc = pbuf[d & 1];
        if (d == 0) {
            atom_mlp<16, true><<<N_ATOMS / 4, 256, 0, stream>>>(
                prop, pp0_w1, pp0_b1, pp_w2, pp_b2, res0_w, Hhi, Hlo, acc);
        } else {
            const float* pin = pbuf[(d - 1) & 1];
            atom_mlp<64, false><<<N_ATOMS / 4, 256, 0, stream>>>(
                pin, pp_w1 + (d - 1) * 4096, pp_b1 + (d - 1) * 64,
                pp_w2 + d * 4096, pp_b2 + d * 64, nullptr, Hhi, Hlo, acc);
        }
        pair_kernel<<<512, 512, 0, stream>>>(
            Hhi, Hlo, ind2, basis,
            img1 + d * 16384, img2 + d * 32768, imgab + d * 16384,
            pi_b1 + d * 64, b2p + d * 256, acc);
        out_kernel<<<N_ATOMS / 4, 256, 0, stream>>>(
            acc, out_w1 + d * 4096, out_b1 + d * 64,
            out_w2 + d * 4096, out_b2 + d * 64, out_wo + d * 64,
            out, d == 0 ? 1 : 0);
    }
}

// Round 8
// 1358.912 us; speedup vs baseline: 1.8595x; 1.8595x over previous
//
#include <hip/hip_runtime.h>
#include <hip/hip_bf16.h>

#define N_ATOMS 25000
#define N_PAIRS 500000
#define DEPTH 4

typedef _Float16 f16x8 __attribute__((ext_vector_type(8)));
typedef float f32x16 __attribute__((ext_vector_type(16)));

__device__ __forceinline__ float tanh_fast(float x) {
    float e = __expf(2.0f * x);
    return 1.0f - 2.0f * __builtin_amdgcn_rcpf(e + 1.0f);
}

// ---------------- prep: fp16-hi fragment-major weight images
// img1 per depth: [ntw][ks(8)][l(64)][j(8)]            = 8192 f16
// img2 per depth: [ntw*4+t][ks(4)][l][j]               = 16384 f16 (cols permuted n=4*ch+t)
// imgab per depth: [stage][ntw][ks(4)][l][j]           = 8192 f16
__global__ __launch_bounds__(256)
void prep_kernel(const float* __restrict__ piW1, const float* __restrict__ piW2,
                 const float* __restrict__ iiW1, const float* __restrict__ iiW2,
                 _Float16* __restrict__ img1, _Float16* __restrict__ img2,
                 _Float16* __restrict__ imgab) {
    int gid = blockIdx.x * 256 + threadIdx.x;   // 512 blocks * 256 = 131072 = 4*32768
    int d = gid >> 15, e = gid & 32767;
    if (e < 8192) {                 // W1 [k=128][n=64]
        int k = e >> 6, n = e & 63;
        int ntw = n >> 5, colb = n & 31;
        int ks = k >> 4, lh = (k >> 3) & 1, j = k & 7;
        img1[d * 8192 + ((ntw * 8 + ks) * 64 + lh * 32 + colb) * 8 + j] =
            (_Float16)piW1[d * 8192 + e];
    } else if (e < 24576) {         // W2 [k=64][n=256], permuted n = 4*ch + t
        int s = e - 8192;
        int k = s >> 8, n = s & 255;
        int ch = n >> 2, t = n & 3;
        int ntw = ch >> 5, colb = ch & 31;
        int ks = k >> 4, lh = (k >> 3) & 1, j = k & 7;
        img2[d * 16384 + (((ntw * 4 + t) * 4 + ks) * 64 + lh * 32 + colb) * 8 + j] =
            (_Float16)piW2[d * 16384 + s];
    } else {                        // ii_w1 (stage0) / ii_w2 (stage1), [k=64][n=64]
        int ep = e - 24576;
        int stage = ep >> 12, s = ep & 4095;
        int k = s >> 6, n = s & 63;
        float x = stage ? iiW2[d * 4096 + s] : iiW1[d * 4096 + s];
        int ntw = n >> 5, colb = n & 31;
        int ks = k >> 4, lh = (k >> 3) & 1, j = k & 7;
        imgab[d * 8192 + stage * 4096 + ((ntw * 4 + ks) * 64 + lh * 32 + colb) * 8 + j] =
            (_Float16)x;
    }
}

__global__ __launch_bounds__(256)
void prep_b2(const float* __restrict__ piB2, float* __restrict__ b2p) {
    int d = blockIdx.x, n = threadIdx.x;
    int ch = n >> 2, t = n & 3;
    int np = (ch >> 5) * 128 + t * 32 + (ch & 31);
    b2p[d * 256 + np] = piB2[d * 256 + n];
}

// ---------------- atom-level MLP (fp32 VALU), h stored fp16
template <int K, bool IS_D0>
__global__ __launch_bounds__(256)
void atom_mlp(const float* __restrict__ p_in,
              const float* __restrict__ W1, const float* __restrict__ b1,
              const float* __restrict__ W2, const float* __restrict__ b2,
              const float* __restrict__ res0_w,
              _Float16* __restrict__ h_out, float* __restrict__ acc_out) {
    __shared__ float sP[4][64];
    __shared__ float sH[4][64];
    int tid = threadIdx.x;
    int al = tid >> 6, c = tid & 63;
    int a = blockIdx.x * 4 + al;
    if (c < K) sP[al][c] = p_in[a * K + c];
    __syncthreads();
    float s = b1[c];
#pragma unroll
    for (int k = 0; k < K; ++k) s += sP[al][k] * W1[k * 64 + c];
    float t1 = tanh_fast(s);
    float r;
    if (IS_D0) {
        r = 0.f;
#pragma unroll
        for (int k = 0; k < 16; ++k) r += sP[al][k] * res0_w[k * 64 + c];
    } else {
        r = sP[al][c];
    }
    acc_out[a * 64 + c] = r;
    sH[al][c] = t1;
    __syncthreads();
    float s2 = b2[c];
#pragma unroll
    for (int k = 0; k < 64; ++k) s2 += sH[al][k] * W2[k * 64 + c];
    h_out[a * 64 + c] = (_Float16)tanh_fast(s2);
}

// ---------------- output head (fp32)
__global__ __launch_bounds__(256)
void out_kernel(const float* __restrict__ p,
                const float* __restrict__ W1, const float* __restrict__ b1,
                const float* __restrict__ W2, const float* __restrict__ b2,
                const float* __restrict__ wo,
                float* __restrict__ out, int store) {
    __shared__ float sP[4][64];
    __shared__ float sH[4][64];
    int tid = threadIdx.x;
    int al = tid >> 6, c = tid & 63;
    int a = blockIdx.x * 4 + al;
    sP[al][c] = p[a * 64 + c];
    __syncthreads();
    float s = b1[c];
#pragma unroll
    for (int k = 0; k < 64; ++k) s += sP[al][k] * W1[k * 64 + c];
    sH[al][c] = tanh_fast(s);
    __syncthreads();
    float s2 = b2[c];
#pragma unroll
    for (int k = 0; k < 64; ++k) s2 += sH[al][k] * W2[k * 64 + c];
    float v = tanh_fast(s2) * wo[c];
#pragma unroll
    for (int off = 32; off > 0; off >>= 1) v += __shfl_down(v, off, 64);
    if (c == 0) {
        if (store) out[a] = v;
        else out[a] += v;
    }
}

// ---------------- fused pair pipeline: fp16 MFMA, all weights CU-resident
// (W1/ii in VGPRs, W2 in LDS), 80 KB LDS -> 2 blocks/CU, fully swizzled LDS
#define MFMA __builtin_amdgcn_mfma_f32_32x32x16_f16

__global__ __launch_bounds__(512, 4)
void pair_kernel(const _Float16* __restrict__ hh,
                 const int* __restrict__ ind2,
                 const float* __restrict__ basis,
                 const _Float16* __restrict__ img1,
                 const _Float16* __restrict__ img2,
                 const _Float16* __restrict__ imgab,
                 const float* __restrict__ piB1,
                 const float* __restrict__ b2p,
                 float* __restrict__ accp) {
    __shared__ __attribute__((aligned(16))) _Float16 sR[16384];   // 32 KB A-frags (K=128); [0:8192] aliased as X2
    __shared__ __attribute__((aligned(16))) _Float16 sX[8192];    // 16 KB X1 / X3
    __shared__ __attribute__((aligned(16))) _Float16 sW2[16384];  // 32 KB W2-hi
    // total 80 KB exactly -> 2 blocks/CU

    const int tid = threadIdx.x;
    for (int i = tid; i < 2048; i += 512) ((uint4*)sW2)[i] = ((const uint4*)img2)[i];

    const int l = tid & 63;
    const int w = tid >> 6;
    const int mt = w >> 1, ntw = w & 1;
    const int col = l & 31, kg = l >> 5;
    const int ch = ntw * 32 + col;
    const int chks = ch >> 4, chlh = (ch >> 3) & 1, chj = ch & 7;
    // X C-store / A-read swizzle (verified R6: 0 conflicts)
    const int rr2 = (chks * 2 + chlh) ^ (kg << 2);
    const int cbase = (mt * 4 + chks) * 512 + chlh * 256 + (rr2 << 3) + chj;
    const int abase = kg * 256 + ((col ^ kg) << 3);

    // persistent register weights: W1-hi (8 frags), ii_w1/ii_w2 hi (8 frags)
    f16x8 w1h[8], fa[4], fb[4];
#pragma unroll
    for (int ks = 0; ks < 8; ++ks)
        w1h[ks] = *(const f16x8*)(img1 + ntw * 4096 + ks * 512 + l * 8);
#pragma unroll
    for (int ks = 0; ks < 4; ++ks) {
        fa[ks] = *(const f16x8*)(imgab + ntw * 2048 + ks * 512 + l * 8);
        fb[ks] = *(const f16x8*)(imgab + 4096 + ntw * 2048 + ks * 512 + l * 8);
    }
    const float b1v = piB1[ch];
    float b2v[4];
#pragma unroll
    for (int t = 0; t < 4; ++t) b2v[t] = b2p[ntw * 128 + t * 32 + col];

    const int nTiles = (N_PAIRS + 127) >> 7;

    // gather: coalesced 16B chunks; LDS writes swizzled (lrow ^ (ks*2+lh)) -> 2-way max
    auto gather_now = [&](int tile) {
        int base = tile << 7;
#pragma unroll
        for (int it = 0; it < 4; ++it) {
            int id = it * 512 + tid;
            int m = id >> 4, half = (id >> 3) & 1, seg = id & 7;
            int p = min(base + m, N_PAIRS - 1);
            int row = ind2[2 * p + half];
            uint4 v = *(const uint4*)(hh + row * 64 + seg * 8);
            int ks = half * 4 + (seg >> 1), lh = seg & 1;
            *(uint4*)(sR + (( (m >> 5) * 8 + ks) * 512 + lh * 256 +
                            (((m & 31) ^ (ks * 2 + lh)) << 3))) = v;
        }
    };
    gather_now(blockIdx.x);
    __syncthreads();

    for (int tile = blockIdx.x; tile < nTiles; tile += gridDim.x) {
        const int base = tile << 7;

        // ---- G1: [128x128]@W1hi + b1, tanh -> sX  (A from sR, swizzled read)
        {
            f32x16 acc = {};
#pragma unroll
            for (int ks = 0; ks < 8; ++ks) {
                f16x8 a = *(const f16x8*)(sR + (mt * 8 + ks) * 512 + kg * 256 +
                                          ((col ^ (ks * 2 + kg)) << 3));
                acc = MFMA(a, w1h[ks], acc, 0, 0, 0);
            }
#pragma unroll
            for (int r = 0; r < 16; ++r) {
                const int Lc = (r & 3) + 8 * (r >> 2);
                sX[cbase ^ (Lc << 3)] = (_Float16)tanh_fast(acc[r] + b1v);
            }
        }
        __syncthreads();

        // ---- G2: @W2hi(LDS) + b2, tanh, basis contraction -> X2 in sR[0:8192]
        {
            float inter[16];
#pragma unroll
            for (int r = 0; r < 16; ++r) inter[r] = 0.f;
#pragma unroll
            for (int t = 0; t < 4; ++t) {
                f32x16 acc = {};
#pragma unroll
                for (int ks = 0; ks < 4; ++ks) {
                    f16x8 a = *(const f16x8*)(sX + (mt * 4 + ks) * 512 + (abase ^ (ks << 4)));
                    f16x8 b = *(const f16x8*)(sW2 + ((ntw * 4 + t) * 4 + ks) * 512 + l * 8);
                    acc = MFMA(a, b, acc, 0, 0, 0);
                }
#pragma unroll
                for (int r = 0; r < 16; ++r) {
                    const int Lc = (r & 3) + 8 * (r >> 2);
                    int p = min(base + mt * 32 + Lc + 4 * kg, N_PAIRS - 1);
                    float bs = basis[4 * p + t];   // 32-lane broadcast, L1/L2-cached
                    inter[r] += tanh_fast(acc[r] + b2v[t]) * bs;
                }
            }
#pragma unroll
            for (int r = 0; r < 16; ++r) {
                const int Lc = (r & 3) + 8 * (r >> 2);
                sR[cbase ^ (Lc << 3)] = (_Float16)inter[r];
            }
        }
        __syncthreads();

        // ---- G3: X2 @ ii_w1(hi, regs), tanh -> sX
        {
            f32x16 acc = {};
#pragma unroll
            for (int ks = 0; ks < 4; ++ks) {
                f16x8 a = *(const f16x8*)(sR + (mt * 4 + ks) * 512 + (abase ^ (ks << 4)));
                acc = MFMA(a, fa[ks], acc, 0, 0, 0);
            }
#pragma unroll
            for (int r = 0; r < 16; ++r) {
                const int Lc = (r & 3) + 8 * (r >> 2);
                sX[cbase ^ (Lc << 3)] = (_Float16)tanh_fast(acc[r]);
            }
        }
        __syncthreads();

        // ---- G4: @ ii_w2(hi, regs), tanh, atomic scatter; gather(next) overlapped
        {
            // issue next-tile gather loads early (latency hidden by G4 compute)
            uint4 gv[4];
            int gaddr[4];
            int gbase = (tile + gridDim.x) << 7;
#pragma unroll
            for (int it = 0; it < 4; ++it) {
                int id = it * 512 + tid;
                int m = id >> 4, half = (id >> 3) & 1, seg = id & 7;
                int p = min(gbase + m, N_PAIRS - 1);
                int row = ind2[2 * p + half];
                gv[it] = *(const uint4*)(hh + row * 64 + seg * 8);
                int ks = half * 4 + (seg >> 1), lh = seg & 1;
                gaddr[it] = ((m >> 5) * 8 + ks) * 512 + lh * 256 +
                            (((m & 31) ^ (ks * 2 + lh)) << 3);
            }

            f32x16 acc = {};
#pragma unroll
            for (int ks = 0; ks < 4; ++ks) {
                f16x8 a = *(const f16x8*)(sX + (mt * 4 + ks) * 512 + (abase ^ (ks << 4)));
                acc = MFMA(a, fb[ks], acc, 0, 0, 0);
            }
#pragma unroll
            for (int r = 0; r < 16; ++r) {
                const int Lc = (r & 3) + 8 * (r >> 2);
                const int p = base + mt * 32 + Lc + 4 * kg;
                if (p < N_PAIRS) {
                    int idx = ind2[2 * p];   // 32-lane broadcast
                    atomicAdd(&accp[idx * 64 + ch], tanh_fast(acc[r]));
                }
            }
            // sink gather ds_writes (sR fully dead: X2 read done at B3)
#pragma unroll
            for (int it = 0; it < 4; ++it) *(uint4*)(sR + gaddr[it]) = gv[it];
        }
        __syncthreads();
    }
}

extern "C" void kernel_launch(void* const* d_in, const int* in_sizes, int n_in,
                              void* d_out, int out_size, void* d_ws, size_t ws_size,
                              hipStream_t stream) {
    const int* ind2 = (const int*)d_in[0];
    const float* prop = (const float*)d_in[1];
    const float* basis = (const float*)d_in[2];
    const float* pp0_w1 = (const float*)d_in[3];
    const float* pp0_b1 = (const float*)d_in[4];
    const float* pp_w1 = (const float*)d_in[5];
    const float* pp_b1 = (const float*)d_in[6];
    const float* pp_w2 = (const float*)d_in[7];
    const float* pp_b2 = (const float*)d_in[8];
    const float* pi_w1 = (const float*)d_in[9];
    const float* pi_b1 = (const float*)d_in[10];
    const float* pi_w2 = (const float*)d_in[11];
    const float* pi_b2 = (const float*)d_in[12];
    const float* ii_w1 = (const float*)d_in[13];
    const float* ii_w2 = (const float*)d_in[14];
    const float* res0_w = (const float*)d_in[15];
    const float* out_w1 = (const float*)d_in[16];
    const float* out_b1 = (const float*)d_in[17];
    const float* out_w2 = (const float*)d_in[18];
    const float* out_b2 = (const float*)d_in[19];
    const float* out_wo = (const float*)d_in[20];
    float* out = (float*)d_out;

    float* B0 = (float*)d_ws;
    float* B1 = B0 + N_ATOMS * 64;
    _Float16* Hhi = (_Float16*)(B1 + N_ATOMS * 64);
    _Float16* img1 = Hhi + N_ATOMS * 64;      // 4*8192 f16
    _Float16* img2 = img1 + 4 * 8192;         // 4*16384 f16
    _Float16* imgab = img2 + 4 * 16384;       // 4*8192 f16
    float* b2p = (float*)(imgab + 4 * 8192);  // 4*256 f32
    float* pbuf[2] = {B0, B1};

    prep_kernel<<<512, 256, 0, stream>>>(pi_w1, pi_w2, ii_w1, ii_w2, img1, img2, imgab);
    prep_b2<<<4, 256, 0, stream>>>(pi_b2, b2p);

    for (int d = 0; d < DEPTH; ++d) {
        float* acc = pbuf[d & 1];
        if (d == 0) {
            atom_mlp<16, true><<<N_ATOMS / 4, 256, 0, stream>>>(
                prop, pp0_w1, pp0_b1, pp_w2, pp_b2, res0_w, Hhi, acc);
        } else {
            const float* pin = pbuf[(d - 1) & 1];
            atom_mlp<64, false><<<N_ATOMS / 4, 256, 0, stream>>>(
                pin, pp_w1 + (d - 1) * 4096, pp_b1 + (d - 1) * 64,
                pp_w2 + d * 4096, pp_b2 + d * 64, nullptr, Hhi, acc);
        }
        pair_kernel<<<512, 512, 0, stream>>>(
            Hhi, ind2, basis,
            img1 + d * 8192, img2 + d * 16384, imgab + d * 8192,
            pi_b1 + d * 64, b2p + d * 256, acc);
        out_kernel<<<N_ATOMS / 4, 256, 0, stream>>>(
            acc, out_w1 + d * 4096, out_b1 + d * 64,
            out_w2 + d * 4096, out_b2 + d * 64, out_wo + d * 64,
            out, d == 0 ? 1 : 0);
    }
}

// Round 9
// 1341.500 us; speedup vs baseline: 1.8837x; 1.0130x over previous
//
#include <hip/hip_runtime.h>
#include <hip/hip_bf16.h>

#define N_ATOMS 25000
#define N_PAIRS 500000
#define DEPTH 4

typedef _Float16 f16x8 __attribute__((ext_vector_type(8)));
typedef float f32x16 __attribute__((ext_vector_type(16)));

__device__ __forceinline__ float tanh_fast(float x) {
    float e = __expf(2.0f * x);
    return 1.0f - 2.0f * __builtin_amdgcn_rcpf(e + 1.0f);
}

// ---------------- counting sort of pairs by ind_i (ind2 is a fixed input)
__global__ __launch_bounds__(256)
void hist_kernel(const int* __restrict__ ind2, int* __restrict__ hist) {
    int p = blockIdx.x * 256 + threadIdx.x;
    if (p < N_PAIRS) atomicAdd(&hist[ind2[2 * p]], 1);
}

__global__ __launch_bounds__(1024)
void scan_kernel(const int* __restrict__ hist, int* __restrict__ offs) {
    __shared__ int sdata[1024];
    __shared__ int sbase;
    int tid = threadIdx.x;
    if (tid == 0) sbase = 0;
    __syncthreads();
    for (int c = 0; c < N_ATOMS; c += 1024) {
        int v = (c + tid < N_ATOMS) ? hist[c + tid] : 0;
        sdata[tid] = v;
        __syncthreads();
        for (int off = 1; off < 1024; off <<= 1) {
            int t = (tid >= off) ? sdata[tid - off] : 0;
            __syncthreads();
            sdata[tid] += t;
            __syncthreads();
        }
        if (c + tid < N_ATOMS) offs[c + tid] = sbase + sdata[tid] - v;
        __syncthreads();
        if (tid == 1023) sbase += sdata[1023];
        __syncthreads();
    }
}

__global__ __launch_bounds__(256)
void scatter_kernel(const int* __restrict__ ind2, const float* __restrict__ basis,
                    int* __restrict__ offs, int* __restrict__ ind2s,
                    float* __restrict__ basisp) {
    int p = blockIdx.x * 256 + threadIdx.x;
    if (p < N_PAIRS) {
        int i = ind2[2 * p], j = ind2[2 * p + 1];
        int pos = atomicAdd(&offs[i], 1);
        ind2s[2 * pos] = i;
        ind2s[2 * pos + 1] = j;
        ((float4*)basisp)[pos] = ((const float4*)basis)[p];
    }
}

// ---------------- prep: fp16 fragment-major weight images (as R8)
__global__ __launch_bounds__(256)
void prep_kernel(const float* __restrict__ piW1, const float* __restrict__ piW2,
                 const float* __restrict__ iiW1, const float* __restrict__ iiW2,
                 _Float16* __restrict__ img1, _Float16* __restrict__ img2,
                 _Float16* __restrict__ imgab) {
    int gid = blockIdx.x * 256 + threadIdx.x;
    int d = gid >> 15, e = gid & 32767;
    if (e < 8192) {
        int k = e >> 6, n = e & 63;
        int ntw = n >> 5, colb = n & 31;
        int ks = k >> 4, lh = (k >> 3) & 1, j = k & 7;
        img1[d * 8192 + ((ntw * 8 + ks) * 64 + lh * 32 + colb) * 8 + j] =
            (_Float16)piW1[d * 8192 + e];
    } else if (e < 24576) {
        int s = e - 8192;
        int k = s >> 8, n = s & 255;
        int ch = n >> 2, t = n & 3;
        int ntw = ch >> 5, colb = ch & 31;
        int ks = k >> 4, lh = (k >> 3) & 1, j = k & 7;
        img2[d * 16384 + (((ntw * 4 + t) * 4 + ks) * 64 + lh * 32 + colb) * 8 + j] =
            (_Float16)piW2[d * 16384 + s];
    } else {
        int ep = e - 24576;
        int stage = ep >> 12, s = ep & 4095;
        int k = s >> 6, n = s & 63;
        float x = stage ? iiW2[d * 4096 + s] : iiW1[d * 4096 + s];
        int ntw = n >> 5, colb = n & 31;
        int ks = k >> 4, lh = (k >> 3) & 1, j = k & 7;
        imgab[d * 8192 + stage * 4096 + ((ntw * 4 + ks) * 64 + lh * 32 + colb) * 8 + j] =
            (_Float16)x;
    }
}

__global__ __launch_bounds__(256)
void prep_b2(const float* __restrict__ piB2, float* __restrict__ b2p) {
    int d = blockIdx.x, n = threadIdx.x;
    int ch = n >> 2, t = n & 3;
    int np = (ch >> 5) * 128 + t * 32 + (ch & 31);
    b2p[d * 256 + np] = piB2[d * 256 + n];
}

// ---------------- depth-0 atom MLP (h from prop; acc init = prop@res0_w)
__global__ __launch_bounds__(256)
void atom_mlp0(const float* __restrict__ p_in,
               const float* __restrict__ W1, const float* __restrict__ b1,
               const float* __restrict__ W2, const float* __restrict__ b2,
               const float* __restrict__ res0_w,
               _Float16* __restrict__ h_out, float* __restrict__ acc_out) {
    __shared__ float sP[4][16];
    __shared__ float sH[4][64];
    int tid = threadIdx.x;
    int al = tid >> 6, c = tid & 63;
    int a = blockIdx.x * 4 + al;
    if (c < 16) sP[al][c] = p_in[a * 16 + c];
    __syncthreads();
    float s = b1[c], r = 0.f;
#pragma unroll
    for (int k = 0; k < 16; ++k) {
        s += sP[al][k] * W1[k * 64 + c];
        r += sP[al][k] * res0_w[k * 64 + c];
    }
    acc_out[a * 64 + c] = r;
    sH[al][c] = tanh_fast(s);
    __syncthreads();
    float s2 = b2[c];
#pragma unroll
    for (int k = 0; k < 64; ++k) s2 += sH[al][k] * W2[k * 64 + c];
    h_out[a * 64 + c] = (_Float16)tanh_fast(s2);
}

// ---------------- fused: output head for depth d + atom MLP for depth d+1
template <bool DO_ATOM>
__global__ __launch_bounds__(256)
void out_atom_kernel(const float* __restrict__ p_in,
                     const float* __restrict__ oW1, const float* __restrict__ ob1,
                     const float* __restrict__ oW2, const float* __restrict__ ob2,
                     const float* __restrict__ wo, float* __restrict__ out, int store,
                     const float* __restrict__ aW1, const float* __restrict__ ab1,
                     const float* __restrict__ aW2, const float* __restrict__ ab2,
                     _Float16* __restrict__ h_out, float* __restrict__ acc_next) {
    __shared__ float sP[4][64];
    __shared__ float sH[4][64];
    __shared__ float sH2[4][64];
    int tid = threadIdx.x;
    int al = tid >> 6, c = tid & 63;
    int a = blockIdx.x * 4 + al;
    float pv = p_in[a * 64 + c];
    sP[al][c] = pv;
    __syncthreads();
    float s1 = ob1[c];
    float s2 = DO_ATOM ? ab1[c] : 0.f;
#pragma unroll
    for (int k = 0; k < 64; ++k) {
        float p = sP[al][k];
        s1 += p * oW1[k * 64 + c];
        if (DO_ATOM) s2 += p * aW1[k * 64 + c];
    }
    sH[al][c] = tanh_fast(s1);
    if (DO_ATOM) sH2[al][c] = tanh_fast(s2);
    __syncthreads();
    float t1 = ob2[c];
    float t2 = DO_ATOM ? ab2[c] : 0.f;
#pragma unroll
    for (int k = 0; k < 64; ++k) {
        t1 += sH[al][k] * oW2[k * 64 + c];
        if (DO_ATOM) t2 += sH2[al][k] * aW2[k * 64 + c];
    }
    if (DO_ATOM) {
        h_out[a * 64 + c] = (_Float16)tanh_fast(t2);
        acc_next[a * 64 + c] = pv;   // residual carry for next depth
    }
    float v = tanh_fast(t1) * wo[c];
#pragma unroll
    for (int off = 32; off > 0; off >>= 1) v += __shfl_down(v, off, 64);
    if (c == 0) {
        if (store) out[a] = v;
        else out[a] += v;
    }
}

// ---------------- fused pair pipeline (R8 structure; sorted pairs; quad-merged atomics)
#define MFMA __builtin_amdgcn_mfma_f32_32x32x16_f16

__global__ __launch_bounds__(512, 4)
void pair_kernel(const _Float16* __restrict__ hh,
                 const int* __restrict__ ind2s,
                 const float* __restrict__ basisp,
                 const _Float16* __restrict__ img1,
                 const _Float16* __restrict__ img2,
                 const _Float16* __restrict__ imgab,
                 const float* __restrict__ piB1,
                 const float* __restrict__ b2p,
                 float* __restrict__ accp) {
    __shared__ __attribute__((aligned(16))) _Float16 sR[16384];   // A-frags; [0:8192] aliased as X2
    __shared__ __attribute__((aligned(16))) _Float16 sX[8192];
    __shared__ __attribute__((aligned(16))) _Float16 sW2[16384];
    // 80 KB -> 2 blocks/CU

    const int tid = threadIdx.x;
    for (int i = tid; i < 2048; i += 512) ((uint4*)sW2)[i] = ((const uint4*)img2)[i];

    const int l = tid & 63;
    const int w = tid >> 6;
    const int mt = w >> 1, ntw = w & 1;
    const int col = l & 31, kg = l >> 5;
    const int ch = ntw * 32 + col;
    const int chks = ch >> 4, chlh = (ch >> 3) & 1, chj = ch & 7;
    const int rr2 = (chks * 2 + chlh) ^ (kg << 2);
    const int cbase = (mt * 4 + chks) * 512 + chlh * 256 + (rr2 << 3) + chj;
    const int abase = kg * 256 + ((col ^ kg) << 3);

    f16x8 w1h[8], fa[4], fb[4];
#pragma unroll
    for (int ks = 0; ks < 8; ++ks)
        w1h[ks] = *(const f16x8*)(img1 + ntw * 4096 + ks * 512 + l * 8);
#pragma unroll
    for (int ks = 0; ks < 4; ++ks) {
        fa[ks] = *(const f16x8*)(imgab + ntw * 2048 + ks * 512 + l * 8);
        fb[ks] = *(const f16x8*)(imgab + 4096 + ntw * 2048 + ks * 512 + l * 8);
    }
    const float b1v = piB1[ch];
    float b2v[4];
#pragma unroll
    for (int t = 0; t < 4; ++t) b2v[t] = b2p[ntw * 128 + t * 32 + col];

    const int nTiles = (N_PAIRS + 127) >> 7;
    // contiguous tile chunk per block: concurrent CUs touch disjoint atom ranges
    const int t0 = (int)(((long)nTiles * blockIdx.x) / gridDim.x);
    const int t1 = (int)(((long)nTiles * (blockIdx.x + 1)) / gridDim.x);

    auto gather_now = [&](int tile) {
        int base = tile << 7;
#pragma unroll
        for (int it = 0; it < 4; ++it) {
            int id = it * 512 + tid;
            int m = id >> 4, half = (id >> 3) & 1, seg = id & 7;
            int p = min(base + m, N_PAIRS - 1);
            int row = ind2s[2 * p + half];
            uint4 v = *(const uint4*)(hh + row * 64 + seg * 8);
            int ks = half * 4 + (seg >> 1), lh = seg & 1;
            *(uint4*)(sR + (((m >> 5) * 8 + ks) * 512 + lh * 256 +
                            (((m & 31) ^ (ks * 2 + lh)) << 3))) = v;
        }
    };
    if (t0 < t1) gather_now(t0);
    __syncthreads();

    for (int tile = t0; tile < t1; ++tile) {
        const int base = tile << 7;

        // ---- G1: [128x128]@W1(regs) + b1, tanh -> sX
        {
            f32x16 acc = {};
#pragma unroll
            for (int ks = 0; ks < 8; ++ks) {
                f16x8 a = *(const f16x8*)(sR + (mt * 8 + ks) * 512 + kg * 256 +
                                          ((col ^ (ks * 2 + kg)) << 3));
                acc = MFMA(a, w1h[ks], acc, 0, 0, 0);
            }
#pragma unroll
            for (int r = 0; r < 16; ++r) {
                const int Lc = (r & 3) + 8 * (r >> 2);
                sX[cbase ^ (Lc << 3)] = (_Float16)tanh_fast(acc[r] + b1v);
            }
        }
        __syncthreads();

        // ---- G2: @W2(LDS) + b2, tanh, basis contraction -> X2 in sR[0:8192]
        {
            float inter[16];
#pragma unroll
            for (int r = 0; r < 16; ++r) inter[r] = 0.f;
#pragma unroll
            for (int t = 0; t < 4; ++t) {
                f32x16 acc = {};
#pragma unroll
                for (int ks = 0; ks < 4; ++ks) {
                    f16x8 a = *(const f16x8*)(sX + (mt * 4 + ks) * 512 + (abase ^ (ks << 4)));
                    f16x8 b = *(const f16x8*)(sW2 + ((ntw * 4 + t) * 4 + ks) * 512 + l * 8);
                    acc = MFMA(a, b, acc, 0, 0, 0);
                }
#pragma unroll
                for (int r = 0; r < 16; ++r) {
                    const int Lc = (r & 3) + 8 * (r >> 2);
                    int p = min(base + mt * 32 + Lc + 4 * kg, N_PAIRS - 1);
                    float bs = basisp[4 * p + t];
                    inter[r] += tanh_fast(acc[r] + b2v[t]) * bs;
                }
            }
#pragma unroll
            for (int r = 0; r < 16; ++r) {
                const int Lc = (r & 3) + 8 * (r >> 2);
                sR[cbase ^ (Lc << 3)] = (_Float16)inter[r];
            }
        }
        __syncthreads();

        // ---- G3: X2 @ ii_w1(regs), tanh -> sX
        {
            f32x16 acc = {};
#pragma unroll
            for (int ks = 0; ks < 4; ++ks) {
                f16x8 a = *(const f16x8*)(sR + (mt * 4 + ks) * 512 + (abase ^ (ks << 4)));
                acc = MFMA(a, fa[ks], acc, 0, 0, 0);
            }
#pragma unroll
            for (int r = 0; r < 16; ++r) {
                const int Lc = (r & 3) + 8 * (r >> 2);
                sX[cbase ^ (Lc << 3)] = (_Float16)tanh_fast(acc[r]);
            }
        }
        __syncthreads();

        // ---- G4: @ ii_w2(regs), tanh, run-merged atomic scatter; next-tile gather overlapped
        {
            uint4 gv[4];
            int gaddr[4];
            int gbase = (tile + 1) << 7;
#pragma unroll
            for (int it = 0; it < 4; ++it) {
                int id = it * 512 + tid;
                int m = id >> 4, half = (id >> 3) & 1, seg = id & 7;
                int p = min(gbase + m, N_PAIRS - 1);
                int row = ind2s[2 * p + half];
                gv[it] = *(const uint4*)(hh + row * 64 + seg * 8);
                int ks = half * 4 + (seg >> 1), lh = seg & 1;
                gaddr[it] = ((m >> 5) * 8 + ks) * 512 + lh * 256 +
                            (((m & 31) ^ (ks * 2 + lh)) << 3);
            }

            f32x16 acc = {};
#pragma unroll
            for (int ks = 0; ks < 4; ++ks) {
                f16x8 a = *(const f16x8*)(sX + (mt * 4 + ks) * 512 + (abase ^ (ks << 4)));
                acc = MFMA(a, fb[ks], acc, 0, 0, 0);
            }
            // quad rows are consecutive sorted pairs -> merge equal-ind_i runs
#pragma unroll
            for (int q = 0; q < 4; ++q) {
                int prevIdx = -1;
                float accum = 0.f;
#pragma unroll
                for (int i2 = 0; i2 < 4; ++i2) {
                    int r = q * 4 + i2;
                    int p = base + mt * 32 + 8 * q + 4 * kg + i2;
                    float v = tanh_fast(acc[r]);
                    int idx = (p < N_PAIRS) ? ind2s[2 * p] : -1;
                    if (idx != prevIdx) {
                        if (prevIdx >= 0) atomicAdd(&accp[prevIdx * 64 + ch], accum);
                        prevIdx = idx;
                        accum = v;
                    } else {
                        accum += v;
                    }
                }
                if (prevIdx >= 0) atomicAdd(&accp[prevIdx * 64 + ch], accum);
            }
#pragma unroll
            for (int it = 0; it < 4; ++it) *(uint4*)(sR + gaddr[it]) = gv[it];
        }
        __syncthreads();
    }
}

extern "C" void kernel_launch(void* const* d_in, const int* in_sizes, int n_in,
                              void* d_out, int out_size, void* d_ws, size_t ws_size,
                              hipStream_t stream) {
    const int* ind2 = (const int*)d_in[0];
    const float* prop = (const float*)d_in[1];
    const float* basis = (const float*)d_in[2];
    const float* pp0_w1 = (const float*)d_in[3];
    const float* pp0_b1 = (const float*)d_in[4];
    const float* pp_w1 = (const float*)d_in[5];
    const float* pp_b1 = (const float*)d_in[6];
    const float* pp_w2 = (const float*)d_in[7];
    const float* pp_b2 = (const float*)d_in[8];
    const float* pi_w1 = (const float*)d_in[9];
    const float* pi_b1 = (const float*)d_in[10];
    const float* pi_w2 = (const float*)d_in[11];
    const float* pi_b2 = (const float*)d_in[12];
    const float* ii_w1 = (const float*)d_in[13];
    const float* ii_w2 = (const float*)d_in[14];
    const float* res0_w = (const float*)d_in[15];
    const float* out_w1 = (const float*)d_in[16];
    const float* out_b1 = (const float*)d_in[17];
    const float* out_w2 = (const float*)d_in[18];
    const float* out_b2 = (const float*)d_in[19];
    const float* out_wo = (const float*)d_in[20];
    float* out = (float*)d_out;

    // workspace layout
    float* B0 = (float*)d_ws;                   // 1.6M f32
    float* B1 = B0 + N_ATOMS * 64;              // 1.6M f32
    _Float16* Hhi = (_Float16*)(B1 + N_ATOMS * 64);   // 1.6M f16
    _Float16* img1 = Hhi + N_ATOMS * 64;        // 4*8192 f16
    _Float16* img2 = img1 + 4 * 8192;           // 4*16384 f16
    _Float16* imgab = img2 + 4 * 16384;         // 4*8192 f16
    float* b2p = (float*)(imgab + 4 * 8192);    // 4*256 f32
    int* hist = (int*)(b2p + 4 * 256);          // 25000 int
    int* offs = hist + N_ATOMS;                 // 25000 int
    int* ind2s = offs + N_ATOMS;                // 1M int
    float* basisp = (float*)(ind2s + 2 * N_PAIRS);  // 2M f32 (16B aligned)
    float* pbuf[2] = {B0, B1};

    // pair sort by ind_i (once per launch; ind2 is fixed input)
    hipMemsetAsync(hist, 0, N_ATOMS * sizeof(int), stream);
    hist_kernel<<<(N_PAIRS + 255) / 256, 256, 0, stream>>>(ind2, hist);
    scan_kernel<<<1, 1024, 0, stream>>>(hist, offs);
    scatter_kernel<<<(N_PAIRS + 255) / 256, 256, 0, stream>>>(ind2, basis, offs, ind2s, basisp);
    prep_kernel<<<512, 256, 0, stream>>>(pi_w1, pi_w2, ii_w1, ii_w2, img1, img2, imgab);
    prep_b2<<<4, 256, 0, stream>>>(pi_b2, b2p);

    for (int d = 0; d < DEPTH; ++d) {
        float* acc = pbuf[d & 1];
        if (d == 0) {
            atom_mlp0<<<N_ATOMS / 4, 256, 0, stream>>>(
                prop, pp0_w1, pp0_b1, pp_w2, pp_b2, res0_w, Hhi, acc);
        }
        pair_kernel<<<512, 512, 0, stream>>>(
            Hhi, ind2s, basisp,
            img1 + d * 8192, img2 + d * 16384, imgab + d * 8192,
            pi_b1 + d * 64, b2p + d * 256, acc);
        if (d < DEPTH - 1) {
            // fused: out(d) + atom_mlp(d+1): h(d+1), acc(d+1) = p(d) copy
            float* accN = pbuf[(d + 1) & 1];
            out_atom_kernel<true><<<N_ATOMS / 4, 256, 0, stream>>>(
                acc, out_w1 + d * 4096, out_b1 + d * 64,
                out_w2 + d * 4096, out_b2 + d * 64, out_wo + d * 64,
                out, d == 0 ? 1 : 0,
                pp_w1 + d * 4096, pp_b1 + d * 64,
                pp_w2 + (d + 1) * 4096, pp_b2 + (d + 1) * 64,
                Hhi, accN);
        } else {
            out_atom_kernel<false><<<N_ATOMS / 4, 256, 0, stream>>>(
                acc, out_w1 + d * 4096, out_b1 + d * 64,
                out_w2 + d * 4096, out_b2 + d * 64, out_wo + d * 64,
                out, 0,
                nullptr, nullptr, nullptr, nullptr, nullptr, nullptr);
        }
    }
}